// Round 7
// baseline (494.339 us; speedup 1.0000x reference)
//
#include <hip/hip_runtime.h>
#include <hip/hip_bf16.h>
#include <stdint.h>

#define DEVI __device__ __forceinline__

typedef __attribute__((ext_vector_type(8))) short bf16x8;
typedef __attribute__((ext_vector_type(4))) short bf16x4;
typedef __attribute__((ext_vector_type(4))) float f32x4;

// Problem constants (B=2, S=2048, D=2048, H=16, HD=128)
static constexpr int S_  = 2048;
static constexpr int H_  = 16;
static constexpr int HD_ = 128;

DEVI short f2bf(float f){                 // RNE float -> bf16
  uint32_t u = __builtin_bit_cast(uint32_t, f);
  u += 0x7fffu + ((u >> 16) & 1u);
  return (short)(u >> 16);
}
DEVI float bf2f(short s){
  uint32_t u = ((uint32_t)(uint16_t)s) << 16;
  return __builtin_bit_cast(float, u);
}

// async global->LDS, 16B per lane; lds_base must be wave-uniform (HW adds lane*16)
DEVI void gll16(const short* g, const short* lds_base){
  __builtin_amdgcn_global_load_lds(
      (const __attribute__((address_space(1))) void*)g,
      (__attribute__((address_space(3))) void*)lds_base,
      16, 0, 0);
}

// ---------------- fp32 -> bf16 convert, 6 slabs of 1,048,576 float4 ----------------
// slab 0,1: x -> XB ; 2: wq -> WQKV ; 3: wk -> WQKV+4M ; 4: wv -> WQKV+8M ; 5: wo -> WO
__global__ __launch_bounds__(256)
void cvt6_kernel(const float* __restrict__ x,  const float* __restrict__ wq,
                 const float* __restrict__ wk, const float* __restrict__ wv,
                 const float* __restrict__ wo,
                 short* __restrict__ XB, short* __restrict__ WQKV, short* __restrict__ WO)
{
  const float* src; short* dst;
  switch (blockIdx.y){
    case 0:  src = x;           dst = XB;             break;
    case 1:  src = x + 4194304; dst = XB + 4194304;   break;
    case 2:  src = wq;          dst = WQKV;           break;
    case 3:  src = wk;          dst = WQKV + 4194304; break;
    case 4:  src = wv;          dst = WQKV + 8388608; break;
    default: src = wo;          dst = WO;             break;
  }
  int i = blockIdx.x * 256 + threadIdx.x;     // [0, 1048576)
  float4 v = ((const float4*)src)[i];
  bf16x4 o;
  o[0] = f2bf(v.x); o[1] = f2bf(v.y); o[2] = f2bf(v.z); o[3] = f2bf(v.w);
  ((bf16x4*)dst)[i] = o;
}

// ---------------- bt-GEMM: C[m][n] = sum_k A[m][k]*Bw[n][k] ----------------
// 128x128 tile, BK=32, 4 waves (2x2), each wave 64x64 (4x4 frags of 16x16x32).
// EPI==0: fp32 C store.  EPI==1: QKV scatter epilogue (bf16):
//   n in [0,2048)    -> Qo[bh][s][d]
//   n in [2048,4096) -> Ko[bh][s][d]
//   n in [4096,6144) -> Vo[bh][d][s]   (V stored transposed)
template<int EPI>
__global__ __launch_bounds__(256)
void gemm_bt(const short* __restrict__ A, const short* __restrict__ Bw,
             float* __restrict__ Cout, short* __restrict__ Qo,
             short* __restrict__ Ko, short* __restrict__ Vo,
             int M, int N, int K)
{
  __shared__ short As[128*32];
  __shared__ short Bs[128*32];
  int tiles_m = M >> 7;
  int bm = (int)blockIdx.x % tiles_m;
  int bn = (int)blockIdx.x / tiles_m;
  int tid = threadIdx.x;
  int w = tid >> 6, l = tid & 63;
  int l15 = l & 15, lg = l >> 4;
  int wr = w >> 1, wc = w & 1;

  f32x4 acc[4][4];
#pragma unroll
  for (int i = 0; i < 4; ++i)
#pragma unroll
    for (int j = 0; j < 4; ++j) acc[i][j] = 0;

  for (int k0 = 0; k0 < K; k0 += 32){
#pragma unroll
    for (int j = 0; j < 2; ++j){
      int c = j*256 + w*64 + l;          // chunk id, 16B each
      int row = c >> 2, kc = c & 3;
      gll16(A  + ((size_t)(bm*128 + row))*K + k0 + kc*8, As + (j*256 + w*64)*8);
      gll16(Bw + ((size_t)(bn*128 + row))*K + k0 + kc*8, Bs + (j*256 + w*64)*8);
    }
    __syncthreads();
    bf16x8 af[4], bfv[4];
#pragma unroll
    for (int i = 0; i < 4; ++i){
      af[i]  = *(const bf16x8*)(As + (wr*64 + i*16 + l15)*32 + lg*8);
      bfv[i] = *(const bf16x8*)(Bs + (wc*64 + i*16 + l15)*32 + lg*8);
    }
#pragma unroll
    for (int i = 0; i < 4; ++i)
#pragma unroll
      for (int j = 0; j < 4; ++j)
        acc[i][j] = __builtin_amdgcn_mfma_f32_16x16x32_bf16(af[i], bfv[j], acc[i][j], 0, 0, 0);
    __syncthreads();
  }

#pragma unroll
  for (int i = 0; i < 4; ++i){
#pragma unroll
    for (int j = 0; j < 4; ++j){
      int m0 = bm*128 + wr*64 + i*16 + lg*4;
      int n  = bn*128 + wc*64 + j*16 + l15;
      if (EPI == 0){
#pragma unroll
        for (int r = 0; r < 4; ++r)
          Cout[(size_t)(m0 + r)*N + n] = acc[i][j][r];
      } else {
        int sect = n >> 11;              // uniform across the wave
        int nn = n & 2047;
        int h = nn >> 7, d = nn & 127;
        if (sect == 2){
          int b = m0 >> 11, s = m0 & 2047;       // 4 rows stay in one b (tiles 128-aligned)
          bf16x4 pv;
#pragma unroll
          for (int r = 0; r < 4; ++r) pv[r] = f2bf(acc[i][j][r]);
          *(bf16x4*)(Vo + (((size_t)(b*H_ + h))*HD_ + d)*S_ + s) = pv;
        } else {
          short* dst = (sect == 0) ? Qo : Ko;
#pragma unroll
          for (int r = 0; r < 4; ++r){
            int m = m0 + r; int b = m >> 11, s = m & 2047;
            dst[(((size_t)(b*H_ + h))*S_ + s)*HD_ + d] = f2bf(acc[i][j][r]);
          }
        }
      }
    }
  }
}

// ---------------- RoPE (in-place on [BH][S][128] bf16) ----------------
__global__ __launch_bounds__(256)
void rope_kernel(short* __restrict__ q, short* __restrict__ k,
                 const float* __restrict__ fr){
  int idx = blockIdx.x * 256 + threadIdx.x;   // BH*S*16 total
  short* p = (blockIdx.y == 0) ? q : k;
  int t = idx & 15, row = idx >> 4;
  int s = row & (S_ - 1);
  short* ptr = p + (size_t)row*HD_ + t*8;
  bf16x8 v = *(bf16x8*)ptr;
  const float* f = fr + ((size_t)s*64 + t*4)*2;   // 4 (cos,sin) pairs, contiguous
  float4 f0 = *(const float4*)f;
  float4 f1 = *(const float4*)(f + 4);
  bf16x8 o;
  float a, b;
  a = bf2f(v[0]); b = bf2f(v[1]); o[0] = f2bf(a*f0.x - b*f0.y); o[1] = f2bf(a*f0.y + b*f0.x);
  a = bf2f(v[2]); b = bf2f(v[3]); o[2] = f2bf(a*f0.z - b*f0.w); o[3] = f2bf(a*f0.w + b*f0.z);
  a = bf2f(v[4]); b = bf2f(v[5]); o[4] = f2bf(a*f1.x - b*f1.y); o[5] = f2bf(a*f1.y + b*f1.x);
  a = bf2f(v[6]); b = bf2f(v[7]); o[6] = f2bf(a*f1.z - b*f1.w); o[7] = f2bf(a*f1.w + b*f1.z);
  *(bf16x8*)ptr = o;
}

// ---------------- flash attention with tanh softcap + causal ----------------
// grid (S/128, BH) = (16, 32). Block bx handles q-tiles {bx, 31-bx} (64 rows
// each) so every block runs exactly (bx+1)+(32-bx) = 33 kt-iterations —
// balanced critical path with all 512 blocks co-resident.
// 4 waves; wave w owns q rows [qt*64 + w*16, +16).
// K: [BH][S][128]; Vt: [BH][128][S]; out: [B][S][H*128] bf16.
__global__ __launch_bounds__(256)
void attn_kernel(const short* __restrict__ Q, const short* __restrict__ Kg,
                 const short* __restrict__ Vt, short* __restrict__ Ob)
{
  __shared__ short Ks[64*136];   // 64 kv rows x 128d (+8 pad)
  __shared__ short Vs[128*72];   // 128 d rows  x 64kv (+8 pad)
  __shared__ short Ps[4][16*72]; // per-wave P[16 q][64 kv] (+8 pad)
  int bx = blockIdx.x, bh = blockIdx.y;
  int tid = threadIdx.x;
  int w = tid >> 6, l = tid & 63, l15 = l & 15, lg = l >> 4;
  int b = bh >> 4, h = bh & 15;
  const float LOG2E = 1.4426950408889634f;

  for (int pass = 0; pass < 2; ++pass){
    int qt = pass ? (31 - bx) : bx;
    int q0 = qt*64 + w*16;

    bf16x8 qf[4];
    {
      const short* qp = Q + ((size_t)bh*S_ + q0 + l15)*HD_ + lg*8;
#pragma unroll
      for (int kc = 0; kc < 4; ++kc) qf[kc] = *(const bf16x8*)(qp + kc*32);
    }
    f32x4 o[8];
#pragma unroll
    for (int dt = 0; dt < 8; ++dt) o[dt] = 0;
    float mrow[4], lrow[4];
#pragma unroll
    for (int r = 0; r < 4; ++r){ mrow[r] = -1e30f; lrow[r] = 0.f; }

    for (int kt = 0; kt <= qt; ++kt){
      int kv0 = kt*64;
      __syncthreads();           // protect Ks/Vs from previous iter/pass readers
#pragma unroll
      for (int j = 0; j < 4; ++j){   // stage K tile: 1024 x 16B chunks
        int c = tid + j*256; int row = c >> 4, k8 = c & 15;
        *(bf16x8*)(Ks + row*136 + k8*8) =
          *(const bf16x8*)(Kg + ((size_t)bh*S_ + kv0 + row)*HD_ + k8*8);
      }
#pragma unroll
      for (int j = 0; j < 4; ++j){   // stage Vt tile
        int c = tid + j*256; int d = c >> 3, k8 = c & 7;
        *(bf16x8*)(Vs + d*72 + k8*8) =
          *(const bf16x8*)(Vt + ((size_t)bh*HD_ + d)*S_ + kv0 + k8*8);
      }
      __syncthreads();

      f32x4 sa[4];
#pragma unroll
      for (int tj = 0; tj < 4; ++tj) sa[tj] = 0;
#pragma unroll
      for (int tj = 0; tj < 4; ++tj)
#pragma unroll
        for (int kc = 0; kc < 4; ++kc){
          bf16x8 kf = *(const bf16x8*)(Ks + (tj*16 + l15)*136 + kc*32 + lg*8);
          sa[tj] = __builtin_amdgcn_mfma_f32_16x16x32_bf16(qf[kc], kf, sa[tj], 0, 0, 0);
        }

      // scale + tanh softcap + causal mask
#pragma unroll
      for (int tj = 0; tj < 4; ++tj)
#pragma unroll
        for (int r = 0; r < 4; ++r){
          float sc = sa[tj][r] * 0.08838834764831845f;   // 1/sqrt(128)
          float y = sc * 0.02f;                          // /50
          float ay = fabsf(y);
          float e = exp2f(ay * (-2.0f * LOG2E));
          float th = __fdividef(1.0f - e, 1.0f + e);
          th = (y < 0.f) ? -th : th;
          sc = 50.0f * th;
          if (kt == qt){
            int kcol = kv0 + tj*16 + l15;
            int qrow = q0 + lg*4 + r;
            if (kcol > qrow) sc = -1e9f;
          }
          sa[tj][r] = sc;
        }

      // online softmax (rows live on 16-lane groups)
#pragma unroll
      for (int r = 0; r < 4; ++r){
        float tm = fmaxf(fmaxf(sa[0][r], sa[1][r]), fmaxf(sa[2][r], sa[3][r]));
#pragma unroll
        for (int off = 1; off < 16; off <<= 1) tm = fmaxf(tm, __shfl_xor(tm, off, 64));
        float mn = fmaxf(mrow[r], tm);
        float scl = exp2f((mrow[r] - mn) * LOG2E);
        mrow[r] = mn;
        lrow[r] *= scl;
#pragma unroll
        for (int dt = 0; dt < 8; ++dt) o[dt][r] *= scl;
        float ts = 0.f;
#pragma unroll
        for (int tj = 0; tj < 4; ++tj){
          float p = exp2f((sa[tj][r] - mn) * LOG2E);
          sa[tj][r] = p;
          ts += p;
        }
#pragma unroll
        for (int off = 1; off < 16; off <<= 1) ts += __shfl_xor(ts, off, 64);
        lrow[r] += ts;
      }

      // transpose P through per-wave LDS (write scattered b16, read b128 A-frags)
      short* ps = &Ps[w][0];
#pragma unroll
      for (int tj = 0; tj < 4; ++tj)
#pragma unroll
        for (int r = 0; r < 4; ++r)
          ps[(lg*4 + r)*72 + tj*16 + l15] = f2bf(sa[tj][r]);
      bf16x8 pa0 = *(const bf16x8*)(ps + l15*72 + lg*8);
      bf16x8 pa1 = *(const bf16x8*)(ps + l15*72 + 32 + lg*8);

#pragma unroll
      for (int dt = 0; dt < 8; ++dt){
        bf16x8 v0 = *(const bf16x8*)(Vs + (dt*16 + l15)*72 + lg*8);
        bf16x8 v1 = *(const bf16x8*)(Vs + (dt*16 + l15)*72 + 32 + lg*8);
        o[dt] = __builtin_amdgcn_mfma_f32_16x16x32_bf16(pa0, v0, o[dt], 0, 0, 0);
        o[dt] = __builtin_amdgcn_mfma_f32_16x16x32_bf16(pa1, v1, o[dt], 0, 0, 0);
      }
    }

    // normalize + store [B][S][H*HD] bf16
    float inv[4];
#pragma unroll
    for (int r = 0; r < 4; ++r) inv[r] = __fdividef(1.0f, lrow[r]);
#pragma unroll
    for (int dt = 0; dt < 8; ++dt)
#pragma unroll
      for (int r = 0; r < 4; ++r){
        int qrow = q0 + lg*4 + r;
        Ob[((size_t)(b*S_ + qrow))*(H_*HD_) + h*HD_ + dt*16 + l15] = f2bf(o[dt][r] * inv[r]);
      }
  }
}

// ---------------- launcher ----------------
extern "C" void kernel_launch(void* const* d_in, const int* in_sizes, int n_in,
                              void* d_out, int out_size, void* d_ws, size_t ws_size,
                              hipStream_t stream)
{
  const float* x  = (const float*)d_in[0];
  const float* fr = (const float*)d_in[1];
  // d_in[2] = mask (unused; causal applied analytically)
  const float* wq = (const float*)d_in[3];
  const float* wk = (const float*)d_in[4];
  const float* wv = (const float*)d_in[5];
  const float* wo = (const float*)d_in[6];
  float* out = (float*)d_out;

  char* ws = (char*)d_ws;
  // layout (bytes): XB 16.8M | WQKV 25.2M | WO 8.4M | QB 16.8M | KB 16.8M | VT 16.8M
  short* XB   = (short*)(ws + 0);            // x bf16 [4096][2048]
  short* WQKV = (short*)(ws + 16777216);     // [6144][2048]
  short* WO   = (short*)(ws + 41943040);     // [2048][2048]
  short* QB   = (short*)(ws + 50331648);     // [BH][S][128]
  short* KB   = (short*)(ws + 67108864);     // [BH][S][128]
  short* VT   = (short*)(ws + 83886080);     // [BH][128][S]
  short* AB   = (short*)(ws + 0);            // attn out [B][S][2048], reuses XB region

  cvt6_kernel<<<dim3(4096, 6), 256, 0, stream>>>(x, wq, wk, wv, wo, XB, WQKV, WO);
  gemm_bt<1><<<dim3(32*48), 256, 0, stream>>>(XB, WQKV, nullptr, QB, KB, VT, 4096, 6144, 2048);
  rope_kernel<<<dim3(4096, 2), 256, 0, stream>>>(QB, KB, fr);
  attn_kernel<<<dim3(16, 32), 256, 0, stream>>>(QB, KB, VT, AB);
  gemm_bt<0><<<dim3(32*16), 256, 0, stream>>>(AB, WO, out, nullptr, nullptr, nullptr, 4096, 2048, 2048);
}